// Round 9
// baseline (131.550 us; speedup 1.0000x reference)
//
#include <hip/hip_runtime.h>

typedef _Float16 half2_t __attribute__((ext_vector_type(2)));
typedef _Float16 half4_t __attribute__((ext_vector_type(4)));
typedef _Float16 half8_t __attribute__((ext_vector_type(8)));
typedef __fp16   fp16x2  __attribute__((ext_vector_type(2)));
typedef float    f32x4   __attribute__((ext_vector_type(4)));

#define BS 128
#define DH 64

__device__ __forceinline__ half2_t pkrtz(float x, float y) {
  fp16x2 t = __builtin_amdgcn_cvt_pkrtz(x, y);
  return __builtin_bit_cast(half2_t, t);
}

__device__ __forceinline__ half8_t cvt8(const float4 a, const float4 b) {
  half2_t h0 = pkrtz(a.x, a.y);
  half2_t h1 = pkrtz(a.z, a.w);
  half2_t h2 = pkrtz(b.x, b.y);
  half2_t h3 = pkrtz(b.z, b.w);
  half4_t lo = __builtin_shufflevector(h0, h1, 0, 1, 2, 3);
  half4_t hi = __builtin_shufflevector(h2, h3, 0, 1, 2, 3);
  return __builtin_shufflevector(lo, hi, 0, 1, 2, 3, 4, 5, 6, 7);
}

// VT swizzle: conflict-free for the transposed half2 write AND the b128 read.
__device__ __forceinline__ int svt(int d) { return (d & 7) ^ ((d >> 2) & 7); }

// No min-waves clamp (R3-R5 spill trap); VGPR demand ~110 -> 4 waves/SIMD tier.
__global__ __launch_bounds__(256) void ball_attn_kernel(
    const float* __restrict__ Q, const float* __restrict__ Kk,
    const float* __restrict__ V, float* __restrict__ O) {
  // Exactly 32 KB -> 4 blocks/CU (VGPR-bound), 16 waves/CU.
  __shared__ __align__(16) _Float16 VT[DH * BS];      // [d][key], svt-swizzled
  __shared__ __align__(16) _Float16 Pl[4 * 16 * BS];  // per-wave P half (reused m=0,1)

  const int tid  = threadIdx.x;
  const int w    = tid >> 6;
  const int lane = tid & 63;
  const int c    = lane & 15;
  const int g    = lane >> 4;

  // XCD-chunked remap: each XCD walks a contiguous range of balls (bijective,
  // gridDim.x = 4096 = 8 * 512) -> sequential streams per XCD L2.
  const int nwg  = gridDim.x;
  const int bid  = blockIdx.x;
  const int ball = (bid & 7) * (nwg >> 3) + (bid >> 3);

  const size_t base = (size_t)ball * (BS * DH);
  const float* Qb = Q + base;
  const float* Kb = Kk + base;
  const float* Vb = V + base;
  float*       Ob = O + base;

  // ---- stage V^T: all 8 loads in ONE burst (32 transient regs, acc not live)
  {
    const int kgrp = tid >> 4;        // 0..15
    const int d0   = (tid & 15) * 4;  // 0..60
    float4 vA[4], vB[4];
#pragma unroll
    for (int it = 0; it < 4; ++it) {
      const int keyA = 2 * kgrp + 32 * it;
      vA[it] = *(const float4*)(Vb + (size_t)keyA * DH + d0);
      vB[it] = *(const float4*)(Vb + (size_t)(keyA + 1) * DH + d0);
    }
#pragma unroll
    for (int it = 0; it < 4; ++it) {
      const int keyA = 2 * kgrp + 32 * it;
      const float* ap = (const float*)&vA[it];
      const float* bp = (const float*)&vB[it];
#pragma unroll
      for (int j = 0; j < 4; ++j) {
        const int d = d0 + j;
        *(half2_t*)&VT[d * BS + (keyA ^ (svt(d) << 3))] = pkrtz(ap[j], bp[j]);
      }
    }
  }

  // ---- Q fragments (4 overlapped loads, cvt immediately) ----
  half8_t aq[2][2];
#pragma unroll
  for (int m = 0; m < 2; ++m)
#pragma unroll
    for (int ks = 0; ks < 2; ++ks) {
      const float* qp = Qb + (w * 32 + m * 16 + c) * DH + ks * 32 + g * 8;
      aq[m][ks] = cvt8(*(const float4*)qp, *(const float4*)(qp + 4));
    }

  __syncthreads();  // VT visible (only barrier in the kernel)

  // ---- QK^T with rolling 2-slot K prefetch (keeps loads in flight) ----
  f32x4 acc[2][8];
#pragma unroll
  for (int m = 0; m < 2; ++m)
#pragma unroll
    for (int kt = 0; kt < 8; ++kt) acc[m][kt] = (f32x4){0.f, 0.f, 0.f, 0.f};

  {
    // step i = kt*2 + ks; K row = kt*16+c, cols ks*32 + g*8 .. +7
    float4 kb[2][2];
    auto kaddr = [&](int i) {
      const int kt = i >> 1, ks = i & 1;
      return Kb + (kt * 16 + c) * DH + ks * 32 + g * 8;
    };
    kb[0][0] = *(const float4*)kaddr(0);
    kb[0][1] = *(const float4*)(kaddr(0) + 4);
    kb[1][0] = *(const float4*)kaddr(1);
    kb[1][1] = *(const float4*)(kaddr(1) + 4);
#pragma unroll
    for (int i = 0; i < 16; ++i) {
      const half8_t bk = cvt8(kb[i & 1][0], kb[i & 1][1]);  // consume slot
      if (i + 2 < 16) {                                      // reissue slot
        kb[i & 1][0] = *(const float4*)kaddr(i + 2);
        kb[i & 1][1] = *(const float4*)(kaddr(i + 2) + 4);
      }
      const int kt = i >> 1, ks = i & 1;
      acc[0][kt] = __builtin_amdgcn_mfma_f32_16x16x32_f16(aq[0][ks], bk, acc[0][kt], 0, 0, 0);
      acc[1][kt] = __builtin_amdgcn_mfma_f32_16x16x32_f16(aq[1][ks], bk, acc[1][kt], 0, 0, 0);
    }
  }

  // ---- per 16-row half: softmax -> P|LDS -> PV -> store ----
#pragma unroll
  for (int m = 0; m < 2; ++m) {
    float mx[4], sm[4], inv[4];
#pragma unroll
    for (int r = 0; r < 4; ++r) {
      mx[r] = acc[m][0][r];
#pragma unroll
      for (int kt = 1; kt < 8; ++kt) mx[r] = fmaxf(mx[r], acc[m][kt][r]);
    }
#pragma unroll
    for (int r = 0; r < 4; ++r) {
      mx[r] = fmaxf(mx[r], __shfl_xor(mx[r], 1));
      mx[r] = fmaxf(mx[r], __shfl_xor(mx[r], 2));
      mx[r] = fmaxf(mx[r], __shfl_xor(mx[r], 4));
      mx[r] = fmaxf(mx[r], __shfl_xor(mx[r], 8));
      sm[r] = 0.f;
    }
#pragma unroll
    for (int kt = 0; kt < 8; ++kt)
#pragma unroll
      for (int r = 0; r < 4; ++r) {
        const float p = __expf((acc[m][kt][r] - mx[r]) * 0.125f);
        acc[m][kt][r] = p;
        sm[r] += p;
      }
#pragma unroll
    for (int r = 0; r < 4; ++r) {
      sm[r] += __shfl_xor(sm[r], 1);
      sm[r] += __shfl_xor(sm[r], 2);
      sm[r] += __shfl_xor(sm[r], 4);
      sm[r] += __shfl_xor(sm[r], 8);
      inv[r] = __builtin_amdgcn_rcpf(sm[r]);  // sum >= 1, safe
    }
    // write P (f16) swizzled; same-wave LDS ordering makes Pl reuse safe
#pragma unroll
    for (int kt = 0; kt < 8; ++kt)
#pragma unroll
      for (int r = 0; r < 4; ++r) {
        const int row = 4 * g + r;
        Pl[(w * 16 + row) * BS + ((kt * 16 + c) ^ ((row & 7) << 3))] =
            (_Float16)acc[m][kt][r];
      }

    // PV: A = P row c (key-contig), B = VT row d (key-contig)
    f32x4 o[4];
#pragma unroll
    for (int t = 0; t < 4; ++t) o[t] = (f32x4){0.f, 0.f, 0.f, 0.f};
#pragma unroll
    for (int ks = 0; ks < 4; ++ks) {
      const int e0 = ks * 32 + g * 8;
      const half8_t pfg = *(const half8_t*)&Pl[(w * 16 + c) * BS + (e0 ^ ((c & 7) << 3))];
#pragma unroll
      for (int t = 0; t < 4; ++t) {
        const int rowd = t * 16 + c;
        const half8_t vf = *(const half8_t*)&VT[rowd * BS + (e0 ^ (svt(rowd) << 3))];
        o[t] = __builtin_amdgcn_mfma_f32_16x16x32_f16(pfg, vf, o[t], 0, 0, 0);
      }
    }
    // store (rows 4g+r, cols t*16+c), scaled by 1/rowsum
#pragma unroll
    for (int t = 0; t < 4; ++t)
#pragma unroll
      for (int r = 0; r < 4; ++r)
        Ob[(w * 32 + m * 16 + 4 * g + r) * DH + t * 16 + c] = o[t][r] * inv[r];
  }
}

extern "C" void kernel_launch(void* const* d_in, const int* in_sizes, int n_in,
                              void* d_out, int out_size, void* d_ws, size_t ws_size,
                              hipStream_t stream) {
  const float* q = (const float*)d_in[0];
  const float* k = (const float*)d_in[1];
  const float* v = (const float*)d_in[2];
  float* out = (float*)d_out;
  const int nballs = in_sizes[0] / (BS * DH);  // 4096
  ball_attn_kernel<<<dim3(nballs), dim3(256), 0, stream>>>(q, k, v, out);
}

// Round 10
// 121.806 us; speedup vs baseline: 1.0800x; 1.0800x over previous
//
#include <hip/hip_runtime.h>

typedef _Float16 half2_t __attribute__((ext_vector_type(2)));
typedef _Float16 half4_t __attribute__((ext_vector_type(4)));
typedef _Float16 half8_t __attribute__((ext_vector_type(8)));
typedef __fp16   fp16x2  __attribute__((ext_vector_type(2)));
typedef float    f32x4   __attribute__((ext_vector_type(4)));

#define BS 128
#define DH 64

__device__ __forceinline__ half2_t pkrtz(float x, float y) {
  fp16x2 t = __builtin_amdgcn_cvt_pkrtz(x, y);
  return __builtin_bit_cast(half2_t, t);
}

__device__ __forceinline__ half8_t cvt8(const float4 a, const float4 b) {
  half2_t h0 = pkrtz(a.x, a.y);
  half2_t h1 = pkrtz(a.z, a.w);
  half2_t h2 = pkrtz(b.x, b.y);
  half2_t h3 = pkrtz(b.z, b.w);
  half4_t lo = __builtin_shufflevector(h0, h1, 0, 1, 2, 3);
  half4_t hi = __builtin_shufflevector(h2, h3, 0, 1, 2, 3);
  return __builtin_shufflevector(lo, hi, 0, 1, 2, 3, 4, 5, 6, 7);
}

// VT swizzle: conflict-free for the transposed half2 write AND the b128 read.
__device__ __forceinline__ int svt(int d) { return (d & 7) ^ ((d >> 2) & 7); }

__global__ __launch_bounds__(256) void ball_attn_kernel(
    const float* __restrict__ Q, const float* __restrict__ Kk,
    const float* __restrict__ V, float* __restrict__ O) {
  // 32 KB (K f32, gload_lds) + 16 KB (VT f16) + 16 KB (Pl) = 64 KB exactly.
  __shared__ __align__(16) float    Kf[BS * DH];      // [key][unit^(key&7)] f32
  __shared__ __align__(16) _Float16 VT[DH * BS];      // [d][key], svt-swizzled
  __shared__ __align__(16) _Float16 Pl[4 * 16 * BS];  // per-wave P half (reused m=0,1)

  const int tid  = threadIdx.x;
  const int w    = tid >> 6;
  const int lane = tid & 63;
  const int c    = lane & 15;
  const int g    = lane >> 4;

  // XCD-chunked remap (bijective: 4096 = 8*512): contiguous ball span per XCD.
  const int nwg  = gridDim.x;
  const int bid  = blockIdx.x;
  const int ball = (bid & 7) * (nwg >> 3) + (bid >> 3);

  const size_t base = (size_t)ball * (BS * DH);
  const float* Qb = Q + base;
  const float* Kb = Kk + base;
  const float* Vb = V + base;
  float*       Ob = O + base;

  // ---- 1) K -> LDS f32 via global_load_lds (no regs, no cvt on this path).
  // Linear LDS dest; per-lane PRE-SWIZZLED global source u = c ^ (row&7)
  // =>  LDS[row][e] = global unit e^(row&7).
#pragma unroll
  for (int t = 0; t < 8; ++t) {
    const int row = 32 * w + 4 * t + g;
    const int u   = c ^ (row & 7);
    __builtin_amdgcn_global_load_lds(
        (const __attribute__((address_space(1))) unsigned int*)(Kb + row * DH + u * 4),
        (__attribute__((address_space(3))) unsigned int*)&Kf[(32 * w + 4 * t) * DH],
        16, 0, 0);
  }

  half8_t aq[2][2];
  // ---- 2) V burst (8 float4 in flight) + 3) Q while V flies + 4) VT write ----
  {
    const int kgrp = tid >> 4;        // 0..15
    const int d0   = (tid & 15) * 4;  // 0..60
    float4 vA[4], vB[4];
#pragma unroll
    for (int it = 0; it < 4; ++it) {
      const int keyA = 2 * kgrp + 32 * it;
      vA[it] = *(const float4*)(Vb + (size_t)keyA * DH + d0);
      vB[it] = *(const float4*)(Vb + (size_t)(keyA + 1) * DH + d0);
    }
#pragma unroll
    for (int m = 0; m < 2; ++m)
#pragma unroll
      for (int ks = 0; ks < 2; ++ks) {
        const float* qp = Qb + (w * 32 + m * 16 + c) * DH + ks * 32 + g * 8;
        aq[m][ks] = cvt8(*(const float4*)qp, *(const float4*)(qp + 4));
      }
#pragma unroll
    for (int it = 0; it < 4; ++it) {
      const int keyA = 2 * kgrp + 32 * it;
      const float* ap = (const float*)&vA[it];
      const float* bp = (const float*)&vB[it];
#pragma unroll
      for (int j = 0; j < 4; ++j) {
        const int d = d0 + j;
        *(half2_t*)&VT[d * BS + (keyA ^ (svt(d) << 3))] = pkrtz(ap[j], bp[j]);
      }
    }
  }

  __syncthreads();  // drains gload_lds (vmcnt) + VT writes; only barrier

  // ---- QK^T from Kf (LDS f32 -> f16 frags); swizzle-matched reads ----
  f32x4 acc[2][8];
#pragma unroll
  for (int m = 0; m < 2; ++m)
#pragma unroll
    for (int kt = 0; kt < 8; ++kt) acc[m][kt] = (f32x4){0.f, 0.f, 0.f, 0.f};

#pragma unroll
  for (int kt = 0; kt < 8; ++kt)
#pragma unroll
    for (int ks = 0; ks < 2; ++ks) {
      const int row = kt * 16 + c;
      const int sr  = row & 7;
      const int u0  = 8 * ks + 2 * g;
      const float4 a = *(const float4*)&Kf[row * DH + ((u0 ^ sr) * 4)];
      const float4 b = *(const float4*)&Kf[row * DH + (((u0 + 1) ^ sr) * 4)];
      const half8_t bk = cvt8(a, b);
      acc[0][kt] = __builtin_amdgcn_mfma_f32_16x16x32_f16(aq[0][ks], bk, acc[0][kt], 0, 0, 0);
      acc[1][kt] = __builtin_amdgcn_mfma_f32_16x16x32_f16(aq[1][ks], bk, acc[1][kt], 0, 0, 0);
    }

  // ---- per 16-row half: softmax -> P|LDS -> PV -> NT store ----
#pragma unroll
  for (int m = 0; m < 2; ++m) {
    float mx[4], sm[4], inv[4];
#pragma unroll
    for (int r = 0; r < 4; ++r) {
      mx[r] = acc[m][0][r];
#pragma unroll
      for (int kt = 1; kt < 8; ++kt) mx[r] = fmaxf(mx[r], acc[m][kt][r]);
    }
#pragma unroll
    for (int r = 0; r < 4; ++r) {
      mx[r] = fmaxf(mx[r], __shfl_xor(mx[r], 1));
      mx[r] = fmaxf(mx[r], __shfl_xor(mx[r], 2));
      mx[r] = fmaxf(mx[r], __shfl_xor(mx[r], 4));
      mx[r] = fmaxf(mx[r], __shfl_xor(mx[r], 8));
      sm[r] = 0.f;
    }
#pragma unroll
    for (int kt = 0; kt < 8; ++kt)
#pragma unroll
      for (int r = 0; r < 4; ++r) {
        const float p = __expf((acc[m][kt][r] - mx[r]) * 0.125f);
        acc[m][kt][r] = p;
        sm[r] += p;
      }
#pragma unroll
    for (int r = 0; r < 4; ++r) {
      sm[r] += __shfl_xor(sm[r], 1);
      sm[r] += __shfl_xor(sm[r], 2);
      sm[r] += __shfl_xor(sm[r], 4);
      sm[r] += __shfl_xor(sm[r], 8);
      inv[r] = __builtin_amdgcn_rcpf(sm[r]);  // sum >= 1, safe
    }
#pragma unroll
    for (int kt = 0; kt < 8; ++kt)
#pragma unroll
      for (int r = 0; r < 4; ++r) {
        const int row = 4 * g + r;
        Pl[(w * 16 + row) * BS + ((kt * 16 + c) ^ ((row & 7) << 3))] =
            (_Float16)acc[m][kt][r];
      }

    // PV: A = P row c (key-contig), B = VT row d (key-contig)
    f32x4 o[4];
#pragma unroll
    for (int t = 0; t < 4; ++t) o[t] = (f32x4){0.f, 0.f, 0.f, 0.f};
#pragma unroll
    for (int ks = 0; ks < 4; ++ks) {
      const int e0 = ks * 32 + g * 8;
      const half8_t pfg = *(const half8_t*)&Pl[(w * 16 + c) * BS + (e0 ^ ((c & 7) << 3))];
#pragma unroll
      for (int t = 0; t < 4; ++t) {
        const int rowd = t * 16 + c;
        const half8_t vf = *(const half8_t*)&VT[rowd * BS + (e0 ^ (svt(rowd) << 3))];
        o[t] = __builtin_amdgcn_mfma_f32_16x16x32_f16(pfg, vf, o[t], 0, 0, 0);
      }
    }
    // NT stores: stream O past L3 so inputs stay resident (FETCH should drop)
#pragma unroll
    for (int t = 0; t < 4; ++t)
#pragma unroll
      for (int r = 0; r < 4; ++r)
        __builtin_nontemporal_store(
            o[t][r] * inv[r], &Ob[(w * 32 + m * 16 + 4 * g + r) * DH + t * 16 + c]);
  }
}

extern "C" void kernel_launch(void* const* d_in, const int* in_sizes, int n_in,
                              void* d_out, int out_size, void* d_ws, size_t ws_size,
                              hipStream_t stream) {
  const float* q = (const float*)d_in[0];
  const float* k = (const float*)d_in[1];
  const float* v = (const float*)d_in[2];
  float* out = (float*)d_out;
  const int nballs = in_sizes[0] / (BS * DH);  // 4096
  ball_attn_kernel<<<dim3(nballs), dim3(256), 0, stream>>>(q, k, v, out);
}